// Round 5
// baseline (92.888 us; speedup 1.0000x reference)
//
#include <hip/hip_runtime.h>

// CreateInstMap: out[r,c] = 1 + argmin_k sqrt((px-cx[k])^2 + (py-cy[k])^2)
//   px = (c+1) - reg[0,r,c], py = (r+1) - reg[1,r,c]; cy=cc[k,0], cx=cc[k,1].
//
// Round 4b (4 + compile fix: clang ext_vector_type for nontemporal builtins;
// HIP float4/int4 are classes and are rejected by __builtin_nontemporal_*).
//  * Amortize per-wave fixed costs (HBM-load latency, shuffle-reduce chains,
//    prune, barrier) over 8 px/thread; 1024 blocks of 32x64-px tiles.
//  * Per-wave prune (8 rows x 64 cols strip): keep k iff
//    d(k,anchor) <= dmin + 2R + 4, R measured from the strip's pred points.
//    Slack 4.0 >> fp error (~1e-2). k-order compaction => first-index ties.
//  * Main loop: argmin on g = ck - 2*sx*cx' - 2*sy*cy' (= d^2 minus a
//    per-pixel constant), wave-anchor-shifted coords; 2 FMA per pixel-cand.
//    Track best + second-best.
//  * Exactness: worst-corner audit: g-gap fp error <= ~4, reference d^2
//    rounding <= ~3, sqrt-collision window <= ~1.2 => TAU=16 is ~2x margin.
//    If any pixel has sec-best <= TAU, the wave re-runs the bit-exact
//    reference chain (__fmul_rn/__fadd_rn/__fsqrt_rn, strict <) over the
//    pruned list, reloading exact reg/cc from global (rare path).

#define H_ 1024
#define W_ 2048
#define K_ 64
#define TAU 16.0f

typedef float  fx4 __attribute__((ext_vector_type(4)));
typedef int    ix4 __attribute__((ext_vector_type(4)));

__global__ __launch_bounds__(256) void inst_map_kernel(
    const float* __restrict__ reg,   // (2, H, W) float32
    const float* __restrict__ cc,    // (K, 2)    float32, [k] = (cy, cx)
    int* __restrict__ out)           // (H, W)    int32
{
    __shared__ float4 cand[4][K_ + 1];  // per wave: (cx', cy', ck, kbits) + pad

    const int tid  = threadIdx.x;
    const int w    = tid >> 6;               // wave id
    const int lane = tid & 63;
    const int tr0  = blockIdx.y * 32;
    const int tc0  = blockIdx.x * 64;
    // wave strip: rows [tr0+8w, tr0+8w+8) x cols [tc0, tc0+64)
    // thread: 2 rows x 4 cols
    const int r0    = tr0 + w * 8 + ((lane >> 4) << 1);
    const int c     = tc0 + ((lane & 15) << 2);
    const int base0 = r0 * W_ + c;
    const int base1 = base0 + W_;

    const fx4 rx0 = __builtin_nontemporal_load(
        reinterpret_cast<const fx4*>(reg + base0));
    const fx4 rx1 = __builtin_nontemporal_load(
        reinterpret_cast<const fx4*>(reg + base1));
    const fx4 ry0 = __builtin_nontemporal_load(
        reinterpret_cast<const fx4*>(reg + H_ * W_ + base0));
    const fx4 ry1 = __builtin_nontemporal_load(
        reinterpret_cast<const fx4*>(reg + H_ * W_ + base1));

    // wave-strip anchor in pred space (pixel coords are 1-based)
    const float ax = (float)tc0 + 32.5f;
    const float ay = (float)(tr0 + w * 8) + 4.5f;

    // shifted coefficients + strip radius. pixel i: row r0+(i>>2), col c+(i&3)
    float pxn[8], pyn[8];
    float m = 0.0f;
    {
        const float rxv[8] = {rx0.x, rx0.y, rx0.z, rx0.w,
                              rx1.x, rx1.y, rx1.z, rx1.w};
        const float ryv[8] = {ry0.x, ry0.y, ry0.z, ry0.w,
                              ry1.x, ry1.y, ry1.z, ry1.w};
        #pragma unroll
        for (int i = 0; i < 8; ++i) {
            const float pxe = (float)(c + (i & 3) + 1) - rxv[i];
            const float pye = (float)(r0 + (i >> 2) + 1) - ryv[i];
            const float sx = pxe - ax, sy = pye - ay;
            pxn[i] = -2.0f * sx;
            pyn[i] = -2.0f * sy;
            m = fmaxf(m, __fmaf_rn(sx, sx, sy * sy));
        }
    }

    // per-lane center, shifted; merged max/min shuffle reduce (chains interleave)
    const float cyk = cc[2 * lane];
    const float cxk = cc[2 * lane + 1];
    const float sxc = cxk - ax, syc = cyk - ay;
    const float ck  = __fmaf_rn(sxc, sxc, syc * syc);
    const float d   = sqrtf(ck);
    float dmin = d;
    #pragma unroll
    for (int s = 1; s < 64; s <<= 1) {
        m    = fmaxf(m,    __shfl_xor(m, s, 64));
        dmin = fminf(dmin, __shfl_xor(dmin, s, 64));
    }

    const bool keep = d <= dmin + 2.0f * sqrtf(m) + 4.0f;
    const unsigned long long mask = __ballot(keep);
    const int ncand = (int)__popcll(mask);
    if (keep) {
        const int pos = (int)__popcll(mask & ((1ull << lane) - 1ull));
        cand[w][pos] = make_float4(sxc, syc, ck, __int_as_float(lane + 1));
    }
    if (lane == 0)   // pad: ck=+inf -> g=+inf, never wins
        cand[w][ncand] = make_float4(0.0f, 0.0f, INFINITY, __int_as_float(1));
    __syncthreads();

    // ---- main loop: 2 FMA per pixel-candidate, best + second-best ----
    float best[8], sec[8];
    int   bidx[8];
    #pragma unroll
    for (int i = 0; i < 8; ++i) { best[i] = INFINITY; sec[i] = INFINITY; bidx[i] = 1; }

    float4 cd = cand[w][0];
    for (int j = 0; j < ncand; ++j) {
        const float4 nx = cand[w][j + 1];      // one-ahead prefetch (pad-safe)
        #pragma unroll
        for (int i = 0; i < 8; ++i) {
            const float g = __fmaf_rn(pxn[i], cd.x,
                            __fmaf_rn(pyn[i], cd.y, cd.z));
            const bool lt = g < best[i];
            const float mn = fminf(sec[i], g);
            sec[i]  = lt ? best[i] : mn;
            best[i] = lt ? g : best[i];
            bidx[i] = lt ? __float_as_int(cd.w) : bidx[i];
        }
        cd = nx;
    }

    // ---- rare exact fallback: bit-exact reference math over survivors ----
    bool haz = false;
    #pragma unroll
    for (int i = 0; i < 8; ++i)
        haz = haz | (sec[i] - best[i] <= TAU);
    if (__any(haz)) {
        // recompute exact reference pred values (reg reload is L2-hot)
        const float4 ex0 = *reinterpret_cast<const float4*>(reg + base0);
        const float4 ex1 = *reinterpret_cast<const float4*>(reg + base1);
        const float4 ey0 = *reinterpret_cast<const float4*>(reg + H_ * W_ + base0);
        const float4 ey1 = *reinterpret_cast<const float4*>(reg + H_ * W_ + base1);
        const float rxv[8] = {ex0.x, ex0.y, ex0.z, ex0.w,
                              ex1.x, ex1.y, ex1.z, ex1.w};
        const float ryv[8] = {ey0.x, ey0.y, ey0.z, ey0.w,
                              ey1.x, ey1.y, ey1.z, ey1.w};
        float px[8], py[8], sb[8];
        int bi2[8];
        #pragma unroll
        for (int i = 0; i < 8; ++i) {
            px[i] = (float)(c + (i & 3) + 1) - rxv[i];
            py[i] = (float)(r0 + (i >> 2) + 1) - ryv[i];
            sb[i] = INFINITY;
            bi2[i] = 1;
        }
        for (int j = 0; j < ncand; ++j) {
            const int kk = __float_as_int(cand[w][j].w);
            const float ecy = cc[2 * (kk - 1)];       // exact coords
            const float ecx = cc[2 * (kk - 1) + 1];
            #pragma unroll
            for (int i = 0; i < 8; ++i) {
                const float dx = px[i] - ecx;
                const float dy = py[i] - ecy;
                const float s2 = __fsqrt_rn(__fadd_rn(__fmul_rn(dx, dx),
                                                      __fmul_rn(dy, dy)));
                const bool lt = s2 < sb[i];           // strict: first-index ties
                sb[i]  = lt ? s2 : sb[i];
                bi2[i] = lt ? kk : bi2[i];
            }
        }
        #pragma unroll
        for (int i = 0; i < 8; ++i) bidx[i] = bi2[i];
    }

    const ix4 o0 = {bidx[0], bidx[1], bidx[2], bidx[3]};
    const ix4 o1 = {bidx[4], bidx[5], bidx[6], bidx[7]};
    __builtin_nontemporal_store(o0, reinterpret_cast<ix4*>(out + base0));
    __builtin_nontemporal_store(o1, reinterpret_cast<ix4*>(out + base1));
}

extern "C" void kernel_launch(void* const* d_in, const int* in_sizes, int n_in,
                              void* d_out, int out_size, void* d_ws, size_t ws_size,
                              hipStream_t stream) {
    const float* reg = (const float*)d_in[0];   // instance_regressions (2,H,W)
    const float* cc  = (const float*)d_in[1];   // center_coords (K,2)
    int* out = (int*)d_out;                     // (H,W) int32

    dim3 grid(W_ / 64, H_ / 32);                // (32, 32) = 1024 blocks
    inst_map_kernel<<<grid, 256, 0, stream>>>(reg, cc, out);
}

// Round 6
// 82.679 us; speedup vs baseline: 1.1235x; 1.1235x over previous
//
#include <hip/hip_runtime.h>

// CreateInstMap: out[r,c] = 1 + argmin_k sqrt((px-cx[k])^2 + (py-cy[k])^2)
//   px = (c+1) - reg[0,r,c], py = (r+1) - reg[1,r,c]; cy=cc[k,0], cx=cc[k,1].
//
// Round 6: remove the unnecessary __syncthreads (each wave owns its cand[w]
// LDS region; intra-wave ds ordering via lgkmcnt is sufficient) — the barrier
// forced 4 waves to converge right after the max-latency-spread point
// (HBM loads + 12-deep shuffle chains). Back to R3's best-measured layout
// (2048 blocks, 32x32 tiles, 4 px/thread, 8x32 wave strips).
//
//  * Per-wave prune: keep k iff d(k,anchor) <= dmin + 2R + 4, with
//    R = max over the strip's pred points of |pred - anchor| (measured).
//    Proof: pruned k has d(k,p) >= d(k,a)-R > dmin+R+4 >= d(j0,p)+4 for the
//    anchor-nearest j0 — margin 4 >> all fp error (~1e-2). k-order
//    compaction preserves first-index tie semantics.
//  * Main loop: BIT-EXACT reference d^2 (__fmul_rn/__fadd_rn on original
//    coords) + strict '<'. Only possible divergence from the reference's
//    sqrt-argmin: new d2 < best but rn(sqrt) ties (ref keeps earlier index).
//    Equal rn(sqrt) implies (best-d2) <= 2^-21*d2; we flag
//    (best-d2) <= 2^-19*d2 (4x margin) -> fallback rate ~2e-6/px (~4 px in
//    the whole image). Fallback: per-wave bit-exact __fsqrt_rn pass.

#define H_ 1024
#define W_ 2048
#define K_ 64
#define HAZC 1.9073486e-6f   // 2^-19

typedef int ix4 __attribute__((ext_vector_type(4)));

__global__ __launch_bounds__(256) void inst_map_kernel(
    const float* __restrict__ reg,   // (2, H, W) float32
    const float* __restrict__ cc,    // (K, 2)    float32, [k] = (cy, cx)
    int* __restrict__ out)           // (H, W)    int32
{
    __shared__ float4 cand[4][K_ + 1];  // per wave: (cx, cy, kbits, 0) + pad

    const int tid  = threadIdx.x;
    const int w    = tid >> 6;               // wave id
    const int lane = tid & 63;
    const int tr0  = blockIdx.y * 32;
    const int tc0  = blockIdx.x * 32;
    const int r    = tr0 + w * 8 + (lane >> 3);   // wave strip: 8 rows x 32 cols
    const int c    = tc0 + ((lane & 7) << 2);     // 4 px/thread
    const int base = r * W_ + c;

    const float4 rx = *reinterpret_cast<const float4*>(reg + base);
    const float4 ry = *reinterpret_cast<const float4*>(reg + H_ * W_ + base);

    // exact reference pred values
    float px[4], py[4];
    const float yf = (float)(r + 1);
    px[0] = (float)(c + 1) - rx.x;  py[0] = yf - ry.x;
    px[1] = (float)(c + 2) - rx.y;  py[1] = yf - ry.y;
    px[2] = (float)(c + 3) - rx.z;  py[2] = yf - ry.z;
    px[3] = (float)(c + 4) - rx.w;  py[3] = yf - ry.w;

    // strip anchor (pixel coords 1-based); strip radius m = max |pred-a|^2
    const float ax = (float)tc0 + 16.5f;
    const float ay = (float)(tr0 + w * 8) + 4.5f;
    float m = 0.0f;
    #pragma unroll
    for (int i = 0; i < 4; ++i) {
        const float sx = px[i] - ax, sy = py[i] - ay;
        m = fmaxf(m, __fmaf_rn(sx, sx, sy * sy));
    }

    // per-lane center distance to anchor; merged max/min shuffle reduce
    const float cyk = cc[2 * lane];
    const float cxk = cc[2 * lane + 1];
    const float sxc = cxk - ax, syc = cyk - ay;
    const float d   = sqrtf(__fmaf_rn(sxc, sxc, syc * syc));
    float dmin = d;
    #pragma unroll
    for (int s = 1; s < 64; s <<= 1) {
        m    = fmaxf(m,    __shfl_xor(m, s, 64));
        dmin = fminf(dmin, __shfl_xor(dmin, s, 64));
    }

    // prune + k-order compaction into this wave's LDS region (no barrier:
    // cand[w] is written and read only by wave w; lgkmcnt orders it)
    const bool keep = d <= dmin + 2.0f * sqrtf(m) + 4.0f;
    const unsigned long long mask = __ballot(keep);
    const int ncand = (int)__popcll(mask);
    if (keep) {
        const int pos = (int)__popcll(mask & ((1ull << lane) - 1ull));
        cand[w][pos] = make_float4(cxk, cyk, __int_as_float(lane + 1), 0.0f);
    }
    if (lane == 0)   // pad: +inf coords -> d2=+inf, never wins, never hazards
        cand[w][ncand] = make_float4(INFINITY, INFINITY, __int_as_float(1), 0.0f);

    // ---- main loop: bit-exact reference d^2, strict '<', hazard flag ----
    float best[4] = {INFINITY, INFINITY, INFINITY, INFINITY};
    int   bidx[4] = {1, 1, 1, 1};
    bool  haz = false;

    float4 cd = cand[w][0];
    for (int j = 0; j < ncand; ++j) {
        const float4 nx = cand[w][j + 1];      // one-ahead prefetch (pad-safe)
        #pragma unroll
        for (int i = 0; i < 4; ++i) {
            const float dx = px[i] - cd.x;
            const float dy = py[i] - cd.y;
            const float d2 = __fadd_rn(__fmul_rn(dx, dx), __fmul_rn(dy, dy));
            const bool lt = d2 < best[i];
            // sqrt-collision hazard: lt but rn(sqrt) could tie with best
            haz = haz | (lt & (best[i] - d2 <= __fmul_rn(d2, HAZC)));
            best[i] = lt ? d2 : best[i];
            bidx[i] = lt ? __float_as_int(cd.z) : bidx[i];
        }
        cd = nx;
    }

    // ---- fallback (~4 px per image): bit-exact sqrt compare ----
    if (__any(haz)) {
        float sb[4]  = {INFINITY, INFINITY, INFINITY, INFINITY};
        int   bi2[4] = {1, 1, 1, 1};
        for (int j = 0; j < ncand; ++j) {
            const float4 c2 = cand[w][j];
            const int kk = __float_as_int(c2.z);
            const float ecy = cc[2 * (kk - 1)];       // exact coords
            const float ecx = cc[2 * (kk - 1) + 1];
            #pragma unroll
            for (int i = 0; i < 4; ++i) {
                const float dx = px[i] - ecx;
                const float dy = py[i] - ecy;
                const float s2 = __fsqrt_rn(__fadd_rn(__fmul_rn(dx, dx),
                                                      __fmul_rn(dy, dy)));
                const bool lt = s2 < sb[i];           // strict: first-index ties
                sb[i]  = lt ? s2 : sb[i];
                bi2[i] = lt ? kk : bi2[i];
            }
        }
        #pragma unroll
        for (int i = 0; i < 4; ++i) bidx[i] = bi2[i];
    }

    const ix4 o = {bidx[0], bidx[1], bidx[2], bidx[3]};
    __builtin_nontemporal_store(o, reinterpret_cast<ix4*>(out + base));
}

extern "C" void kernel_launch(void* const* d_in, const int* in_sizes, int n_in,
                              void* d_out, int out_size, void* d_ws, size_t ws_size,
                              hipStream_t stream) {
    const float* reg = (const float*)d_in[0];   // instance_regressions (2,H,W)
    const float* cc  = (const float*)d_in[1];   // center_coords (K,2)
    int* out = (int*)d_out;                     // (H,W) int32

    dim3 grid(W_ / 32, H_ / 32);                // (64, 32) = 2048 blocks
    inst_map_kernel<<<grid, 256, 0, stream>>>(reg, cc, out);
}